// Round 3
// baseline (325.119 us; speedup 1.0000x reference)
//
#include <hip/hip_runtime.h>
#include <hip/hip_bf16.h>
#include <cstdint>

// Problem constants (match reference)
#define B_ 256
#define N_ 131072
#define D_ 256
#define INV_TEMP 20.0f   // 1/0.05
#define EPS_SM 1e-6f
#define EPS_LOG 1e-6f

// GEMM tiling: 512 blocks (2/CU), each owns 256 cf rows. Chunk = 32 rows x 64 K.
#define TPB 512          // 8 waves; wave w owns A rows w*32..w*32+31
#define BROWS 256        // cf rows per block
#define BN 32            // cf rows per chunk
#define BK 64            // K elems per chunk
#define NCHUNK 32        // (BROWS/BN) * (D_/BK) = 8 * 4
#define LDB 72           // LDS row stride (elems): 64+8 pad, 16B-aligned rows (144B)
#define BUFE (BN * LDB)  // 2304 ushorts = 4.6KB per B buffer
#define NSLOT 32
#define NBLK (N_ / BROWS)  // 512 blocks -> 2 per CU

typedef __bf16 bf16_t;
typedef bf16_t bf16x8 __attribute__((ext_vector_type(8)));
typedef float f32x4 __attribute__((ext_vector_type(4)));

__device__ inline ushort f2bf(float f) {
  uint32_t u = __builtin_bit_cast(uint32_t, f);
  u += 0x7FFFu + ((u >> 16) & 1u);   // round to nearest even
  return (ushort)(u >> 16);
}

// VGPR budget (forced <=128 by launch_bounds(512,4) so 2 blocks/CU fit):
// areg 64 + acc 16 + rs 8 + ldbuf 8 + addressing ~= 115.
__global__ __launch_bounds__(TPB, 4)
void gemm_rowsum_fused(const float* __restrict__ inp, const float* __restrict__ cf,
                       const int* __restrict__ idx, const int* __restrict__ lab,
                       float* __restrict__ rowsum, unsigned* __restrict__ counter,
                       float* __restrict__ out) {
  // 36.8KB: A-stage phase uses [256][LDB]; steady state uses first 2*BUFE as B dbuf.
  __shared__ ushort smem[B_ * LDB];
  __shared__ unsigned done;
  const int tid  = threadIdx.x;
  const int wave = tid >> 6;
  const int lane = tid & 63;
  const int m15  = lane & 15;
  const int q    = lane >> 4;

  const size_t nbase = (size_t)blockIdx.x * BROWS;
  const int brow = tid >> 4, bcg = tid & 15;  // chunk = 32 rows x 64 cols: 16 thr/row x 4 elems
#define LDADDR(c) (cf + (nbase + (size_t)((c) >> 2) * BN + brow) * D_ + ((c) & 3) * BK + bcg * 4)

  // ---- Start the HBM-critical cf stream first (chunks 0,1 -> regs; 16B/thread each).
  float4 ldbuf[2];
  ldbuf[0] = *(const float4*)LDADDR(0);
  ldbuf[1] = *(const float4*)LDADDR(1);

  // ---- A phase (round-0 proven path): coalesced global -> LDS -> MFMA fragments.
  // areg[kc*2+ks][mb]: rows wave*32+mb*16+(lane&15), k = (kc*2+ks)*32 + q*8..+7
  bf16x8 areg[8][2];
#pragma unroll
  for (int kc = 0; kc < 4; ++kc) {
    const int row = tid >> 1, half = tid & 1;
    const float* src = inp + row * D_ + kc * BK + half * 32;
#pragma unroll
    for (int i = 0; i < 8; ++i) {
      const float4 v = *(const float4*)(src + i * 4);
      ushort4 w = {f2bf(v.x), f2bf(v.y), f2bf(v.z), f2bf(v.w)};
      *(ushort4*)(&smem[row * LDB + half * 32 + i * 4]) = w;
    }
    __syncthreads();
#pragma unroll
    for (int mb = 0; mb < 2; ++mb)
#pragma unroll
      for (int ks = 0; ks < 2; ++ks)
        areg[kc * 2 + ks][mb] = __builtin_bit_cast(
            bf16x8, *(const uint4*)(&smem[(wave * 32 + mb * 16 + m15) * LDB + ks * 32 + q * 8]));
    __syncthreads();
  }

  f32x4 acc[2][2];
  float rs[2][4];
#pragma unroll
  for (int mb = 0; mb < 2; ++mb) {
#pragma unroll
    for (int nb = 0; nb < 2; ++nb) acc[mb][nb] = (f32x4){0.f, 0.f, 0.f, 0.f};
#pragma unroll
    for (int r = 0; r < 4; ++r) rs[mb][r] = 0.f;
  }

  // Chunk 0 -> buf 0 (loads issued long ago), then issue chunk 2 (prefetch depth 2).
  {
    const float4 v = ldbuf[0];
    ushort4 w = {f2bf(v.x), f2bf(v.y), f2bf(v.z), f2bf(v.w)};
    *(ushort4*)(&smem[brow * LDB + bcg * 4]) = w;
  }
  ldbuf[0] = *(const float4*)LDADDR(2);

  // ---- Steady state: 32 chunks (N-group = c>>2, kc = c&3), 2 chunks in flight.
#pragma unroll
  for (int c = 0; c < NCHUNK; ++c) {
    __syncthreads();  // buf[c&1] ready; prior reads of buf[(c+1)&1] drained
    const ushort* bs = &smem[(c & 1) * BUFE];
#pragma unroll
    for (int ks = 0; ks < 2; ++ks) {
      bf16x8 bfr[2];
#pragma unroll
      for (int nb = 0; nb < 2; ++nb)
        bfr[nb] = __builtin_bit_cast(
            bf16x8, *(const uint4*)(&bs[(nb * 16 + m15) * LDB + ks * 32 + q * 8]));
#pragma unroll
      for (int mb = 0; mb < 2; ++mb)
#pragma unroll
        for (int nb = 0; nb < 2; ++nb)
          acc[mb][nb] = __builtin_amdgcn_mfma_f32_16x16x32_bf16(
              areg[(c & 3) * 2 + ks][mb], bfr[nb], acc[mb][nb], 0, 0, 0);
    }
    if ((c & 3) == 3) {  // N-group finished: fold exp into register row-sums
#pragma unroll
      for (int mb = 0; mb < 2; ++mb)
#pragma unroll
        for (int nb = 0; nb < 2; ++nb)
#pragma unroll
          for (int r = 0; r < 4; ++r)
            rs[mb][r] += __expf(acc[mb][nb][r] * INV_TEMP);
      if (c + 1 < NCHUNK) {
#pragma unroll
        for (int mb = 0; mb < 2; ++mb)
#pragma unroll
          for (int nb = 0; nb < 2; ++nb) acc[mb][nb] = (f32x4){0.f, 0.f, 0.f, 0.f};
      }
    }
    if (c + 1 < NCHUNK) {  // convert+write chunk c+1 (its loads landed ~2 chunks ago)
      const float4 v = ldbuf[(c + 1) & 1];
      ushort4 w = {f2bf(v.x), f2bf(v.y), f2bf(v.z), f2bf(v.w)};
      *(ushort4*)(&smem[((c + 1) & 1) * BUFE + brow * LDB + bcg * 4]) = w;
    }
    if (c + 3 < NCHUNK) {  // issue chunk c+3 into the slot just freed
      ldbuf[(c + 1) & 1] = *(const float4*)LDADDR(c + 3);
    }
  }

  // C/D layout: col = lane&15 (+ group offsets, folded), row = wave*32 + mb*16 + q*4 + r.
  // Reduce the 16 lanes of each quad, then one atomic batch per wave.
#pragma unroll
  for (int off = 8; off >= 1; off >>= 1)
#pragma unroll
    for (int mb = 0; mb < 2; ++mb)
#pragma unroll
      for (int r = 0; r < 4; ++r)
        rs[mb][r] += __shfl_xor(rs[mb][r], off, 64);

  if (m15 == 0) {
    float* slot = rowsum + (blockIdx.x & (NSLOT - 1)) * B_;
#pragma unroll
    for (int mb = 0; mb < 2; ++mb)
#pragma unroll
      for (int r = 0; r < 4; ++r)
        atomicAdd(&slot[wave * 32 + mb * 16 + q * 4 + r], rs[mb][r]);
  }
#undef LDADDR

  // ---- Fused finalize: last block to finish computes the loss.
  __syncthreads();  // drains this block's atomics (vmcnt(0) before s_barrier)
  if (tid == 0) {
    __threadfence();  // make this block's rowsum atomics device-visible first
    const unsigned prev = __hip_atomic_fetch_add(counter, 1u, __ATOMIC_ACQ_REL,
                                                 __HIP_MEMORY_SCOPE_AGENT);
    done = (prev == (unsigned)(NBLK - 1)) ? 1u : 0u;
  }
  __syncthreads();
  if (done) {
    __threadfence();  // acquire side: order counter observation before rowsum reads
    float* red = (float*)smem;  // reuse LDS: [0,512) dot partials, [512,768) log terms
    const int b = tid >> 1, part = tid & 1;
    const int t = lab[idx[b]];
    const float4* a4 = (const float4*)(inp + b * D_ + part * 128);
    const float4* c4 = (const float4*)(cf + (size_t)t * D_ + part * 128);
    float dot = 0.f;
#pragma unroll
    for (int i = 0; i < 32; ++i) {
      const float4 x = a4[i], y = c4[i];
      dot += x.x * y.x + x.y * y.y + x.z * y.z + x.w * y.w;
    }
    red[tid] = dot;
    __syncthreads();
    if (tid < 256) {
      const float d = red[2 * tid] + red[2 * tid + 1];
      float S = 0.f;
#pragma unroll
      for (int s = 0; s < NSLOT; ++s)
        S += __hip_atomic_load(&rowsum[s * B_ + tid], __ATOMIC_RELAXED,
                               __HIP_MEMORY_SCOPE_AGENT);
      red[512 + tid] = __logf(__expf(d * INV_TEMP) / (S + EPS_SM) + EPS_LOG);
    }
    __syncthreads();
    for (int off = 128; off >= 1; off >>= 1) {
      if (tid < off) red[512 + tid] += red[512 + tid + off];
      __syncthreads();
    }
    if (tid == 0) out[0] = -red[512] * (1.0f / 256.0f);
  }
}

extern "C" void kernel_launch(void* const* d_in, const int* in_sizes, int n_in,
                              void* d_out, int out_size, void* d_ws, size_t ws_size,
                              hipStream_t stream) {
  const float* inp = (const float*)d_in[0];  // inputs [256,256]
  const float* cf  = (const float*)d_in[1];  // cluster_features [131072,256]
  // d_in[2] = instance_features: unused by the reference
  const int* idx = (const int*)d_in[3];      // indexes [256]
  const int* lab = (const int*)d_in[4];      // labels [131072]
  float* out = (float*)d_out;
  float* rowsum = (float*)d_ws;              // NSLOT * 256 floats
  unsigned* counter = (unsigned*)(rowsum + NSLOT * B_);

  hipMemsetAsync(d_ws, 0, (NSLOT * B_ + 16) * sizeof(float), stream);
  gemm_rowsum_fused<<<dim3(NBLK), dim3(TPB), 0, stream>>>(inp, cf, idx, lab,
                                                          rowsum, counter, out);
}